// Round 16
// baseline (1141.444 us; speedup 1.0000x reference)
//
#include <hip/hip_runtime.h>

// Problem dims (fixed)
constexpr int T  = 512;
constexpr int NB = 64;    // batch
constexpr int NI = 128;   // input
constexpr int NH = 512;   // hidden
constexpr int NO = 64;    // output

constexpr float ALPHA = 0.2f;
constexpr float NSC   = 0.063245553203367586f; // 0.1*sqrt(2*ALPHA)

typedef _Float16 h2_t __attribute__((ext_vector_type(2)));

#if defined(__has_builtin)
#  if __has_builtin(__builtin_amdgcn_fdot2)
#    define HAS_FDOT2 1
#  endif
#endif
#ifndef HAS_FDOT2
#  define HAS_FDOT2 0
#endif

__device__ __forceinline__ float dot2(uint32_t wbits, uint32_t hbits, float acc) {
#if HAS_FDOT2
    return __builtin_amdgcn_fdot2(__builtin_bit_cast(h2_t, wbits),
                                  __builtin_bit_cast(h2_t, hbits), acc, false);
#else
    const h2_t wv = __builtin_bit_cast(h2_t, wbits);
    const h2_t hv = __builtin_bit_cast(h2_t, hbits);
    return acc + (float)wv.x * (float)hv.x + (float)wv.y * (float)hv.y;
#endif
}

__device__ __forceinline__ uint32_t pk2(float x, float y) {
    return __builtin_bit_cast(uint32_t, (h2_t){(_Float16)x, (_Float16)y});
}

// ---------------------------------------------------------------------------
// fp32 GEMM, 128-row x TN-col tile, 256 thr, 8 x (TN/16) acc per thread.
// C[M,N] = A[M,K] @ Bm[N,K]^T + bias[N].  FMA:DS ratio 64:4 (TN=128) vs the
// old 64x64 kernel's 16:2 — the GEMMs were ~200us of the total at ~35 TF.
template<int TN>
__global__ __launch_bounds__(256) void k_gemm_t(
    const float* __restrict__ A, const float* __restrict__ Bm,
    const float* __restrict__ bias, float* __restrict__ C,
    int M, int N, int K)
{
    constexpr int NA = TN / 16;                 // cols per thread
    __shared__ __align__(16) float As[16][132];
    __shared__ __align__(16) float Bs[16][TN + 4];
    const int tid = threadIdx.x;
    const int tx = tid & 15, ty = tid >> 4;     // 16 x 16 threads
    const long row0 = (long)blockIdx.x * 128;
    const long col0 = (long)blockIdx.y * TN;

    float acc[8][NA] = {};

    for (int kt = 0; kt < K; kt += 16) {
        __syncthreads();                        // previous-iter reads done
        #pragma unroll
        for (int f = tid; f < 128 * 4; f += 256) {
            const int r = f >> 2, ko = (f & 3) * 4;
            const float4 v = *(const float4*)&A[(row0 + r) * K + kt + ko];
            As[ko+0][r] = v.x; As[ko+1][r] = v.y;
            As[ko+2][r] = v.z; As[ko+3][r] = v.w;
        }
        #pragma unroll
        for (int f = tid; f < TN * 4; f += 256) {
            const int c = f >> 2, ko = (f & 3) * 4;
            const float4 v = *(const float4*)&Bm[(col0 + c) * K + kt + ko];
            Bs[ko+0][c] = v.x; Bs[ko+1][c] = v.y;
            Bs[ko+2][c] = v.z; Bs[ko+3][c] = v.w;
        }
        __syncthreads();
        #pragma unroll
        for (int kk = 0; kk < 16; ++kk) {
            float a[8], b[NA];
            *(float4*)&a[0] = *(const float4*)&As[kk][ty * 8];
            *(float4*)&a[4] = *(const float4*)&As[kk][ty * 8 + 4];
            #pragma unroll
            for (int j = 0; j < NA; j += 4)
                *(float4*)&b[j] = *(const float4*)&Bs[kk][tx * NA + j];
            #pragma unroll
            for (int i = 0; i < 8; ++i)
                #pragma unroll
                for (int j = 0; j < NA; ++j)
                    acc[i][j] += a[i] * b[j];
        }
    }

    #pragma unroll
    for (int i = 0; i < 8; ++i) {
        const long r = row0 + ty * 8 + i;
        const int cc = (int)col0 + tx * NA;
        #pragma unroll
        for (int j = 0; j < NA; j += 4) {
            float4 ov;
            ov.x = acc[i][j+0] + bias[cc + j + 0];
            ov.y = acc[i][j+1] + bias[cc + j + 1];
            ov.z = acc[i][j+2] + bias[cc + j + 2];
            ov.w = acc[i][j+3] + bias[cc + j + 3];
            *(float4*)&C[(size_t)r * N + cc + j] = ov;
        }
    }
}

// ---------------------------------------------------------------------------
// u32 exchange word: [31:16]=f16(h), [15:0]=tag.  R3-proven RMW protocol.
__device__ __forceinline__ uint32_t pack_h(float h, uint32_t tag) {
    const _Float16 hf = (_Float16)h;                    // RNE f32->f16
    const uint32_t hb = __builtin_bit_cast(unsigned short, hf);
    return (hb << 16) | (tag & 0xFFFFu);
}

// ---------------------------------------------------------------------------
// Recurrent kernel = R10 body serving TWO batches per WG (the R16 change).
//  Invariant found over R7-R15: every W-delivery scheme (scratch stream /
//  LDS / VMEM stream) costs ~1us/step because each WG serves ONE batch and
//  must move its 128KB-equivalent W slice every step. 2 batches/WG keeps
//  the same W stream (named scalars -> compiler scratch, reloaded once per
//  step, used by BOTH batches' fdot2s adjacently) but halves per-XCD W
//  bandwidth: 128 WGs x 128KB = 16MB/step vs R10's 32MB.
// Layout: 32 groups (batches {2g,2g+1}) x 4 members; member m owns cols
//  [128m,128m+128); bid = m*32+g (group members equal mod 8 -> same XCD).
//  wave w owns k-chunk [64w,64w+64); lane l -> cols {l, l+64}; h f16 in
//  LDS[2][NH] (16 wave-uniform b128 reads/thread); u32 RMW tagged sync
//  (identical protocol: 2-slot parity t&1, tag t+1, budgeted spin),
//  epilogue threads handle both batches' col gc; pollers handle one peer
//  col x both batches.
__global__ __launch_bounds__(512, 2) void k_rnn(
    const float* __restrict__ W_rec,   // [H][H]
    const float* __restrict__ noise,   // [T][B][H]
    float* __restrict__ rnn,           // [T][B][H]: xin+b_rec in, h out
    uint32_t* __restrict__ ex)         // [2][B][H] tagged words
{
    const int bid = blockIdx.x;    // 0..127
    const int g = bid & 31;        // group
    const int m = bid >> 5;        // member 0..3
    const int tid = threadIdx.x;
    const int w = tid >> 6;        // wave = k-chunk (64 k wide)
    const int l = tid & 63;        // lane -> cols {l, l+64} of slice
    const int b0 = g * 2, b1 = g * 2 + 1;

    __shared__ __align__(16) unsigned short hbf[2][NH];  // f16 h, both batches
    __shared__ __align__(16) float pr[2][8][128];        // per-chunk partials

    // ---- 64 named W scalars (2 cols x 32 packed-f16 words, R10-proven) ----
    uint32_t wa0,wa1,wa2,wa3,wa4,wa5,wa6,wa7,wa8,wa9,wa10,wa11,wa12,wa13,wa14,wa15,
             wa16,wa17,wa18,wa19,wa20,wa21,wa22,wa23,wa24,wa25,wa26,wa27,wa28,wa29,wa30,wa31;
    uint32_t wb0,wb1,wb2,wb3,wb4,wb5,wb6,wb7,wb8,wb9,wb10,wb11,wb12,wb13,wb14,wb15,
             wb16,wb17,wb18,wb19,wb20,wb21,wb22,wb23,wb24,wb25,wb26,wb27,wb28,wb29,wb30,wb31;
    {
        const float* p0 = W_rec + (size_t)(m * 128 + l) * NH + w * 64;
        const float* p1 = W_rec + (size_t)(m * 128 + l + 64) * NH + w * 64;
#define LDW(P, VA, VB, OFF) { const float4 q_ = *(const float4*)((P) + (OFF)); \
                              VA = pk2(q_.x, q_.y); VB = pk2(q_.z, q_.w); }
        LDW(p0, wa0,  wa1,   0) LDW(p0, wa2,  wa3,   4)
        LDW(p0, wa4,  wa5,   8) LDW(p0, wa6,  wa7,  12)
        LDW(p0, wa8,  wa9,  16) LDW(p0, wa10, wa11, 20)
        LDW(p0, wa12, wa13, 24) LDW(p0, wa14, wa15, 28)
        LDW(p0, wa16, wa17, 32) LDW(p0, wa18, wa19, 36)
        LDW(p0, wa20, wa21, 40) LDW(p0, wa22, wa23, 44)
        LDW(p0, wa24, wa25, 48) LDW(p0, wa26, wa27, 52)
        LDW(p0, wa28, wa29, 56) LDW(p0, wa30, wa31, 60)
        LDW(p1, wb0,  wb1,   0) LDW(p1, wb2,  wb3,   4)
        LDW(p1, wb4,  wb5,   8) LDW(p1, wb6,  wb7,  12)
        LDW(p1, wb8,  wb9,  16) LDW(p1, wb10, wb11, 20)
        LDW(p1, wb12, wb13, 24) LDW(p1, wb14, wb15, 28)
        LDW(p1, wb16, wb17, 32) LDW(p1, wb18, wb19, 36)
        LDW(p1, wb20, wb21, 40) LDW(p1, wb22, wb23, 44)
        LDW(p1, wb24, wb25, 48) LDW(p1, wb26, wb27, 52)
        LDW(p1, wb28, wb29, 56) LDW(p1, wb30, wb31, 60)
#undef LDW
    }

    const int gc = m * 128 + tid;            // epilogue col (tid<128)

    // poller mapping (tid>=128): one peer col, both batches
    const int q    = tid - 128;              // 0..383
    const int pp   = q >> 7;                 // 0..2
    const int pm   = pp + (pp >= m ? 1 : 0); // peer member
    const int pcol = pm * 128 + (q & 127);

    hbf[0][tid] = 0; hbf[1][tid] = 0;

    float hreg0 = 0.f, hreg1 = 0.f;          // fp32 h_old (epilogue threads)

    float xin0 = 0.f, noi0 = 0.f, xin1 = 0.f, noi1 = 0.f;
    if (tid < 128) {
        xin0 = rnn[(size_t)b0 * NH + gc];  noi0 = noise[(size_t)b0 * NH + gc];
        xin1 = rnn[(size_t)b1 * NH + gc];  noi1 = noise[(size_t)b1 * NH + gc];
    }
    __syncthreads();

    int alive  = 1;
    int budget = 1 << 16;   // launch-global spin budget (hang-proof)

    for (int t = 0; t < T; ++t) {
        // ---- dot both batches: cols {l, l+64}, k in [64w,64w+64) ----
        float aA0 = 0.f, aA1 = 0.f, aB0 = 0.f, aB1 = 0.f;   // batch b0
        float cA0 = 0.f, cA1 = 0.f, cB0 = 0.f, cB1 = 0.f;   // batch b1
        {
            const uint4* hp0 = (const uint4*)&hbf[0][w * 64];
            const uint4* hp1 = (const uint4*)&hbf[1][w * 64];
#define DOTB(N, A0, A1, A2, A3) { const uint4 u_ = hp0[N]; const uint4 v_ = hp1[N]; \
            aA0 = dot2(wa##A0, u_.x, aA0); cA0 = dot2(wa##A0, v_.x, cA0); \
            aA1 = dot2(wa##A1, u_.y, aA1); cA1 = dot2(wa##A1, v_.y, cA1); \
            aA0 = dot2(wa##A2, u_.z, aA0); cA0 = dot2(wa##A2, v_.z, cA0); \
            aA1 = dot2(wa##A3, u_.w, aA1); cA1 = dot2(wa##A3, v_.w, cA1); \
            aB0 = dot2(wb##A0, u_.x, aB0); cB0 = dot2(wb##A0, v_.x, cB0); \
            aB1 = dot2(wb##A1, u_.y, aB1); cB1 = dot2(wb##A1, v_.y, cB1); \
            aB0 = dot2(wb##A2, u_.z, aB0); cB0 = dot2(wb##A2, v_.z, cB0); \
            aB1 = dot2(wb##A3, u_.w, aB1); cB1 = dot2(wb##A3, v_.w, cB1); }
            DOTB(0,  0,  1,  2,  3)
            DOTB(1,  4,  5,  6,  7)
            DOTB(2,  8,  9, 10, 11)
            DOTB(3, 12, 13, 14, 15)
            DOTB(4, 16, 17, 18, 19)
            DOTB(5, 20, 21, 22, 23)
            DOTB(6, 24, 25, 26, 27)
            DOTB(7, 28, 29, 30, 31)
#undef DOTB
        }
        pr[0][w][l]      = aA0 + aA1;
        pr[0][w][l + 64] = aB0 + aB1;
        pr[1][w][l]      = cA0 + cA1;
        pr[1][w][l + 64] = cB0 + cB1;
        __syncthreads();

        const uint32_t want = (uint32_t)(t + 1);
        uint32_t* slot = ex + (size_t)(t & 1) * NB * NH;

        if (tid < 128) {
            // ---- epilogue: both batches for col gc ----
            float s0 = 0.f, s1 = 0.f;
            #pragma unroll
            for (int k = 0; k < 8; ++k) { s0 += pr[0][k][tid]; s1 += pr[1][k][tid]; }
            const float hn0 = fmaxf(xin0 + s0, 0.f);       // b_rec folded in xin
            const float hn1 = fmaxf(xin1 + s1, 0.f);
            const float nw0 = (1.f - ALPHA) * hreg0 + ALPHA * hn0 + NSC * noi0;
            const float nw1 = (1.f - ALPHA) * hreg1 + ALPHA * hn1 + NSC * noi1;
            hreg0 = nw0; hreg1 = nw1;
            const uint32_t pk0 = pack_h(nw0, want);
            const uint32_t pk1 = pack_h(nw1, want);
            (void)__hip_atomic_exchange(&slot[(size_t)b0 * NH + gc], pk0,
                                        __ATOMIC_RELAXED, __HIP_MEMORY_SCOPE_AGENT);
            (void)__hip_atomic_exchange(&slot[(size_t)b1 * NH + gc], pk1,
                                        __ATOMIC_RELAXED, __HIP_MEMORY_SCOPE_AGENT);
            hbf[0][gc] = (unsigned short)(pk0 >> 16);      // own cols, same rounding
            hbf[1][gc] = (unsigned short)(pk1 >> 16);
            rnn[((size_t)t * NB + b0) * NH + gc] = nw0;
            rnn[((size_t)t * NB + b1) * NH + gc] = nw1;
            const int tn = (t + 1 < T) ? (t + 1) : t;
            xin0 = rnn[((size_t)tn * NB + b0) * NH + gc];
            noi0 = noise[((size_t)tn * NB + b0) * NH + gc];
            xin1 = rnn[((size_t)tn * NB + b1) * NH + gc];
            noi1 = noise[((size_t)tn * NB + b1) * NH + gc];
        } else {
            // ---- gather: poll one peer col for both batches ----
            uint32_t v0, v1;
            if (alive) {
                for (;;) {
                    v0 = __hip_atomic_fetch_or(&slot[(size_t)b0 * NH + pcol], 0u,
                                               __ATOMIC_RELAXED, __HIP_MEMORY_SCOPE_AGENT);
                    if ((v0 & 0xFFFFu) == (want & 0xFFFFu)) break;
                    __builtin_amdgcn_s_sleep(1);
                    if (--budget < 0) { alive = 0; break; }   // fail loudly
                }
                for (;;) {
                    v1 = __hip_atomic_fetch_or(&slot[(size_t)b1 * NH + pcol], 0u,
                                               __ATOMIC_RELAXED, __HIP_MEMORY_SCOPE_AGENT);
                    if ((v1 & 0xFFFFu) == (want & 0xFFFFu)) break;
                    __builtin_amdgcn_s_sleep(1);
                    if (--budget < 0) { alive = 0; break; }
                }
            } else {
                v0 = __hip_atomic_fetch_or(&slot[(size_t)b0 * NH + pcol], 0u,
                                           __ATOMIC_RELAXED, __HIP_MEMORY_SCOPE_AGENT);
                v1 = __hip_atomic_fetch_or(&slot[(size_t)b1 * NH + pcol], 0u,
                                           __ATOMIC_RELAXED, __HIP_MEMORY_SCOPE_AGENT);
            }
            hbf[0][pcol] = (unsigned short)(v0 >> 16);
            hbf[1][pcol] = (unsigned short)(v1 >> 16);
        }
        __syncthreads();
    }
}

// ---------------------------------------------------------------------------
extern "C" void kernel_launch(void* const* d_in, const int* in_sizes, int n_in,
                              void* d_out, int out_size, void* d_ws, size_t ws_size,
                              hipStream_t stream)
{
    (void)in_sizes; (void)n_in; (void)out_size; (void)ws_size;
    const float* x     = (const float*)d_in[0];
    const float* noise = (const float*)d_in[1];
    const float* W_in  = (const float*)d_in[2];
    const float* W_rec = (const float*)d_in[3];
    const float* b_rec = (const float*)d_in[4];
    const float* W_out = (const float*)d_in[5];
    const float* b_out = (const float*)d_in[6];

    float* out = (float*)d_out;                       // [T*B][O]
    float* rnn = out + (size_t)T * NB * NO;           // [T*B][H] (second output)

    uint32_t* ex = (uint32_t*)d_ws;                   // [2][B][H] = 256 KB

    // clear exchange tags (replay-deterministic; tag 0 never polled-for)
    hipMemsetAsync(ex, 0, (size_t)2 * NB * NH * sizeof(uint32_t), stream);

    // xin = x @ W_in^T + b_rec  -> rnn region (in-place consumed)
    hipLaunchKernelGGL((k_gemm_t<128>), dim3((T * NB) / 128, NH / 128), dim3(256), 0,
                       stream, x, W_in, b_rec, rnn, T * NB, NH, NI);

    // sequential recurrence: 128 WGs, 2 batches/WG, f16 fdot2, u32 RMW sync
    hipLaunchKernelGGL(k_rnn, dim3(128), dim3(512), 0, stream,
                       W_rec, noise, rnn, ex);

    // output = rnn @ W_out^T + b_out
    hipLaunchKernelGGL((k_gemm_t<64>), dim3((T * NB) / 128, NO / 64), dim3(256), 0,
                       stream, rnn, W_out, b_out, out, T * NB, NO, NH);
}